// Round 3
// baseline (168.101 us; speedup 1.0000x reference)
//
#include <hip/hip_runtime.h>
#include <math.h>

// SimTALayer == causal softmax attention with score -L*(c_i - c_j) + beta, which
// collapses to an EMA recurrence (beta cancels; upper-tri NINF underflows to 0):
//   a_t = exp(-L*tau_t);  S_t = a_t*S_{t-1} + h_t;  Z_t = a_t*Z_{t-1} + 1;
//   out_t = S_t / Z_t;    h = elu(x @ W^T + b).
// Exact chunked scan, 2 kernels, h recomputed (compute ≪ traffic).
// R3: TC 64→16 (grid 256→1024 blocks, 4→16 waves/CU) to fix the 8% occupancy /
// latency-bound profile of R2. Carry handled in-block via backward suffix-product
// iteration (dependent chain = scalar multiply only) with exact p==0 early-out.

#define BB 4
#define TT 4096
#define DIN 64
#define DM 256
#define TC 16            // chunk length
#define NC (TT / TC)     // 256 chunks per batch; grid = BB*NC = 1024 blocks

// ---------- Kernel 1: per-chunk local scan with fused GEMM+ELU ----------
__global__ __launch_bounds__(256) void k_local(
    const float* __restrict__ x, const float* __restrict__ tau,
    const float* __restrict__ W, const float* __restrict__ bias,
    const float* __restrict__ lamb_p,
    float* __restrict__ SL, float* __restrict__ ZL, float* __restrict__ AK) {
    const int blk = blockIdx.x;
    const int b = blk / NC, c = blk % NC;
    const int t0 = c * TC;
    const int m = threadIdx.x;

    float4 wv[DIN / 4];
    const float4* W4 = reinterpret_cast<const float4*>(W + (size_t)m * DIN);
#pragma unroll
    for (int k = 0; k < DIN / 4; ++k) wv[k] = W4[k];
    const float bm = bias[m];

    __shared__ float as[TC];
    const float L = fmaxf(lamb_p[0], 0.f);
    if (m < TC) as[m] = expf(-L * tau[(size_t)b * TT + t0 + m]);
    __syncthreads();

    const float* xr = x + ((size_t)b * TT + t0) * DIN;
    float S = 0.f, Z = 0.f, A = 1.f;
#pragma unroll
    for (int tg = 0; tg < TC; tg += 4) {
        const float4* xt0 = reinterpret_cast<const float4*>(xr + (size_t)(tg + 0) * DIN);
        const float4* xt1 = reinterpret_cast<const float4*>(xr + (size_t)(tg + 1) * DIN);
        const float4* xt2 = reinterpret_cast<const float4*>(xr + (size_t)(tg + 2) * DIN);
        const float4* xt3 = reinterpret_cast<const float4*>(xr + (size_t)(tg + 3) * DIN);
        float a0 = bm, a1 = bm, a2 = bm, a3 = bm;
#pragma unroll
        for (int k = 0; k < DIN / 4; ++k) {
            const float4 w = wv[k];
            const float4 v0 = xt0[k], v1 = xt1[k], v2 = xt2[k], v3 = xt3[k];
            a0 = fmaf(v0.x, w.x, a0); a0 = fmaf(v0.y, w.y, a0);
            a0 = fmaf(v0.z, w.z, a0); a0 = fmaf(v0.w, w.w, a0);
            a1 = fmaf(v1.x, w.x, a1); a1 = fmaf(v1.y, w.y, a1);
            a1 = fmaf(v1.z, w.z, a1); a1 = fmaf(v1.w, w.w, a1);
            a2 = fmaf(v2.x, w.x, a2); a2 = fmaf(v2.y, w.y, a2);
            a2 = fmaf(v2.z, w.z, a2); a2 = fmaf(v2.w, w.w, a2);
            a3 = fmaf(v3.x, w.x, a3); a3 = fmaf(v3.y, w.y, a3);
            a3 = fmaf(v3.z, w.z, a3); a3 = fmaf(v3.w, w.w, a3);
        }
        const float h0 = a0 > 0.f ? a0 : expm1f(a0);
        const float h1 = a1 > 0.f ? a1 : expm1f(a1);
        const float h2 = a2 > 0.f ? a2 : expm1f(a2);
        const float h3 = a3 > 0.f ? a3 : expm1f(a3);
        float d;
        d = as[tg + 0]; S = fmaf(d, S, h0); Z = fmaf(d, Z, 1.f); A *= d;
        d = as[tg + 1]; S = fmaf(d, S, h1); Z = fmaf(d, Z, 1.f); A *= d;
        d = as[tg + 2]; S = fmaf(d, S, h2); Z = fmaf(d, Z, 1.f); A *= d;
        d = as[tg + 3]; S = fmaf(d, S, h3); Z = fmaf(d, Z, 1.f); A *= d;
    }
    SL[(size_t)blk * DM + m] = S;
    if (m == 0) { ZL[blk] = Z; AK[blk] = A; }
}

// ---------- Kernel 2: in-block carry (suffix-product form) + final scan ----------
__global__ __launch_bounds__(256) void k_final(
    const float* __restrict__ x, const float* __restrict__ tau,
    const float* __restrict__ W, const float* __restrict__ bias,
    const float* __restrict__ lamb_p,
    const float* __restrict__ SL, const float* __restrict__ ZL,
    const float* __restrict__ AK, float* __restrict__ out) {
    const int blk = blockIdx.x;
    const int b = blk / NC, c = blk % NC;
    const int t0 = c * TC;
    const int m = threadIdx.x;

    float4 wv[DIN / 4];
    const float4* W4 = reinterpret_cast<const float4*>(W + (size_t)m * DIN);
#pragma unroll
    for (int k = 0; k < DIN / 4; ++k) wv[k] = W4[k];
    const float bm = bias[m];

    __shared__ float as[TC];
    __shared__ float lA[NC];
    __shared__ float lZ[NC];
    const float L = fmaxf(lamb_p[0], 0.f);
    if (m < TC) as[m] = expf(-L * tau[(size_t)b * TT + t0 + m]);
    lA[m] = AK[b * NC + m];           // DM == NC == 256: one element per thread
    lZ[m] = ZL[b * NC + m];
    __syncthreads();

    // Carry-in S,Z for chunk c = sum over cc<c of SL[cc]*P[cc], P[cc]=prod A[cc+1..c-1].
    // Backward iteration: only the scalar p-multiply is a dependent chain; the
    // S/Z FMAs are independent. p is block-uniform; p==0 break is exact (fma w/ 0).
    float S = 0.f, Z = 0.f;
    {
        const float* SLb = SL + ((size_t)b * NC) * DM + m;
        float p = 1.f;
        for (int cc = c - 1; cc >= 0; --cc) {
            S = fmaf(SLb[(size_t)cc * DM], p, S);
            Z = fmaf(lZ[cc], p, Z);
            p *= lA[cc];
            if (p == 0.f) break;
        }
    }

    const float* xr = x + ((size_t)b * TT + t0) * DIN;
    float* op = out + ((size_t)b * TT + t0) * DM + m;
#pragma unroll
    for (int tg = 0; tg < TC; tg += 4) {
        const float4* xt0 = reinterpret_cast<const float4*>(xr + (size_t)(tg + 0) * DIN);
        const float4* xt1 = reinterpret_cast<const float4*>(xr + (size_t)(tg + 1) * DIN);
        const float4* xt2 = reinterpret_cast<const float4*>(xr + (size_t)(tg + 2) * DIN);
        const float4* xt3 = reinterpret_cast<const float4*>(xr + (size_t)(tg + 3) * DIN);
        float a0 = bm, a1 = bm, a2 = bm, a3 = bm;
#pragma unroll
        for (int k = 0; k < DIN / 4; ++k) {
            const float4 w = wv[k];
            const float4 v0 = xt0[k], v1 = xt1[k], v2 = xt2[k], v3 = xt3[k];
            a0 = fmaf(v0.x, w.x, a0); a0 = fmaf(v0.y, w.y, a0);
            a0 = fmaf(v0.z, w.z, a0); a0 = fmaf(v0.w, w.w, a0);
            a1 = fmaf(v1.x, w.x, a1); a1 = fmaf(v1.y, w.y, a1);
            a1 = fmaf(v1.z, w.z, a1); a1 = fmaf(v1.w, w.w, a1);
            a2 = fmaf(v2.x, w.x, a2); a2 = fmaf(v2.y, w.y, a2);
            a2 = fmaf(v2.z, w.z, a2); a2 = fmaf(v2.w, w.w, a2);
            a3 = fmaf(v3.x, w.x, a3); a3 = fmaf(v3.y, w.y, a3);
            a3 = fmaf(v3.z, w.z, a3); a3 = fmaf(v3.w, w.w, a3);
        }
        const float h0 = a0 > 0.f ? a0 : expm1f(a0);
        const float h1 = a1 > 0.f ? a1 : expm1f(a1);
        const float h2 = a2 > 0.f ? a2 : expm1f(a2);
        const float h3 = a3 > 0.f ? a3 : expm1f(a3);
        float d;
        d = as[tg + 0]; S = fmaf(d, S, h0); Z = fmaf(d, Z, 1.f); op[(size_t)(tg + 0) * DM] = S / Z;
        d = as[tg + 1]; S = fmaf(d, S, h1); Z = fmaf(d, Z, 1.f); op[(size_t)(tg + 1) * DM] = S / Z;
        d = as[tg + 2]; S = fmaf(d, S, h2); Z = fmaf(d, Z, 1.f); op[(size_t)(tg + 2) * DM] = S / Z;
        d = as[tg + 3]; S = fmaf(d, S, h3); Z = fmaf(d, Z, 1.f); op[(size_t)(tg + 3) * DM] = S / Z;
    }
}

extern "C" void kernel_launch(void* const* d_in, const int* in_sizes, int n_in,
                              void* d_out, int out_size, void* d_ws, size_t ws_size,
                              hipStream_t stream) {
    const float* x    = (const float*)d_in[0];  // [B,T,64]
    const float* tau  = (const float*)d_in[1];  // [B,T]
    const float* W    = (const float*)d_in[2];  // [256,64]
    const float* bias = (const float*)d_in[3];  // [256]
    const float* lamb = (const float*)d_in[4];  // [1]
    // beta (d_in[5]) cancels in softmax — unused.
    float* out = (float*)d_out;                 // [B,T,256] fp32

    float* ws = (float*)d_ws;
    float* SL = ws;                         // BB*NC*DM = 262,144 floats (1 MB)
    float* ZL = SL + (size_t)BB * NC * DM;  // BB*NC = 1024
    float* AK = ZL + BB * NC;               // BB*NC = 1024

    k_local<<<BB * NC, DM, 0, stream>>>(x, tau, W, bias, lamb, SL, ZL, AK);
    k_final<<<BB * NC, DM, 0, stream>>>(x, tau, W, bias, lamb, SL, ZL, AK, out);
}

// Round 4
// 161.106 us; speedup vs baseline: 1.0434x; 1.0434x over previous
//
#include <hip/hip_runtime.h>
#include <math.h>

// SimTALayer == causal softmax attention with score -L*(c_i - c_j) + beta, which
// collapses to an EMA recurrence (beta cancels; upper-tri NINF underflows to 0):
//   a_t = exp(-L*tau_t);  S_t = a_t*S_{t-1} + h_t;  Z_t = a_t*Z_{t-1} + 1;
//   out_t = S_t / Z_t;    h = elu(x @ W^T + b).
// Exact chunked scan, 2 kernels, h recomputed (compute ≪ traffic).
// R4: TC=16 (1024 blocks = 4/CU) like R3, but carry early-out is made
// WAVE-UNIFORM via readfirstlane — R3's per-lane break poisoned divergence
// analysis and de-scalarized the x loads (VGPR 44->140, SGPR 112->32, +28% dur).
// Carry loop processes 4 chunks/iter with hoisted loads; p==0 cutoff is exact.

#define BB 4
#define TT 4096
#define DIN 64
#define DM 256
#define TC 16            // chunk length
#define NC (TT / TC)     // 256 chunks per batch; grid = BB*NC = 1024 blocks

// ---------- Kernel 1: per-chunk local scan with fused GEMM+ELU ----------
__global__ __launch_bounds__(256) void k_local(
    const float* __restrict__ x, const float* __restrict__ tau,
    const float* __restrict__ W, const float* __restrict__ bias,
    const float* __restrict__ lamb_p,
    float* __restrict__ SL, float* __restrict__ ZL, float* __restrict__ AK) {
    const int blk = blockIdx.x;
    const int b = blk / NC, c = blk % NC;
    const int t0 = c * TC;
    const int m = threadIdx.x;

    float4 wv[DIN / 4];
    const float4* W4 = reinterpret_cast<const float4*>(W + (size_t)m * DIN);
#pragma unroll
    for (int k = 0; k < DIN / 4; ++k) wv[k] = W4[k];
    const float bm = bias[m];

    __shared__ float as[TC];
    const float L = fmaxf(lamb_p[0], 0.f);
    if (m < TC) as[m] = expf(-L * tau[(size_t)b * TT + t0 + m]);
    __syncthreads();

    const float* xr = x + ((size_t)b * TT + t0) * DIN;
    float S = 0.f, Z = 0.f, A = 1.f;
    for (int tg = 0; tg < TC; tg += 4) {   // rolled: keeps pressure low, loads scalar
        const float4* xt0 = reinterpret_cast<const float4*>(xr + (size_t)(tg + 0) * DIN);
        const float4* xt1 = reinterpret_cast<const float4*>(xr + (size_t)(tg + 1) * DIN);
        const float4* xt2 = reinterpret_cast<const float4*>(xr + (size_t)(tg + 2) * DIN);
        const float4* xt3 = reinterpret_cast<const float4*>(xr + (size_t)(tg + 3) * DIN);
        float a0 = bm, a1 = bm, a2 = bm, a3 = bm;
#pragma unroll
        for (int k = 0; k < DIN / 4; ++k) {
            const float4 w = wv[k];
            const float4 v0 = xt0[k], v1 = xt1[k], v2 = xt2[k], v3 = xt3[k];
            a0 = fmaf(v0.x, w.x, a0); a0 = fmaf(v0.y, w.y, a0);
            a0 = fmaf(v0.z, w.z, a0); a0 = fmaf(v0.w, w.w, a0);
            a1 = fmaf(v1.x, w.x, a1); a1 = fmaf(v1.y, w.y, a1);
            a1 = fmaf(v1.z, w.z, a1); a1 = fmaf(v1.w, w.w, a1);
            a2 = fmaf(v2.x, w.x, a2); a2 = fmaf(v2.y, w.y, a2);
            a2 = fmaf(v2.z, w.z, a2); a2 = fmaf(v2.w, w.w, a2);
            a3 = fmaf(v3.x, w.x, a3); a3 = fmaf(v3.y, w.y, a3);
            a3 = fmaf(v3.z, w.z, a3); a3 = fmaf(v3.w, w.w, a3);
        }
        const float h0 = a0 > 0.f ? a0 : expm1f(a0);
        const float h1 = a1 > 0.f ? a1 : expm1f(a1);
        const float h2 = a2 > 0.f ? a2 : expm1f(a2);
        const float h3 = a3 > 0.f ? a3 : expm1f(a3);
        float d;
        d = as[tg + 0]; S = fmaf(d, S, h0); Z = fmaf(d, Z, 1.f); A *= d;
        d = as[tg + 1]; S = fmaf(d, S, h1); Z = fmaf(d, Z, 1.f); A *= d;
        d = as[tg + 2]; S = fmaf(d, S, h2); Z = fmaf(d, Z, 1.f); A *= d;
        d = as[tg + 3]; S = fmaf(d, S, h3); Z = fmaf(d, Z, 1.f); A *= d;
    }
    SL[(size_t)blk * DM + m] = S;
    if (m == 0) { ZL[blk] = Z; AK[blk] = A; }
}

// ---------- Kernel 2: in-block carry (suffix-product, uniform early-out) ----------
__global__ __launch_bounds__(256) void k_final(
    const float* __restrict__ x, const float* __restrict__ tau,
    const float* __restrict__ W, const float* __restrict__ bias,
    const float* __restrict__ lamb_p,
    const float* __restrict__ SL, const float* __restrict__ ZL,
    const float* __restrict__ AK, float* __restrict__ out) {
    const int blk = blockIdx.x;
    const int b = blk / NC, c = blk % NC;
    const int t0 = c * TC;
    const int m = threadIdx.x;

    float4 wv[DIN / 4];
    const float4* W4 = reinterpret_cast<const float4*>(W + (size_t)m * DIN);
#pragma unroll
    for (int k = 0; k < DIN / 4; ++k) wv[k] = W4[k];
    const float bm = bias[m];

    __shared__ float as[TC];
    __shared__ float lA[NC];
    __shared__ float lZ[NC];
    const float L = fmaxf(lamb_p[0], 0.f);
    if (m < TC) as[m] = expf(-L * tau[(size_t)b * TT + t0 + m]);
    lA[m] = AK[b * NC + m];           // DM == NC == 256: one element per thread
    lZ[m] = ZL[b * NC + m];
    __syncthreads();

    // Carry-in: S,Z = sum_{cc<c} SL[cc]*P, P = prod lA[cc+1..c-1] (backward suffix
    // products). Only the scalar q-chain is dependent; SL loads are independent and
    // hoisted 4-deep. Early-out when p underflows to exact 0 (fma w/ 0 is a no-op);
    // the break is on readfirstlane -> SGPR -> UNIFORM branch (keeps later x loads
    // scalarizable — the R3 regression).
    float S = 0.f, Z = 0.f;
    {
        const float* SLb = SL + ((size_t)b * NC) * DM + m;
        float p = 1.f;
        int cc = c - 1;
        while (cc >= 3) {
            const float s0 = SLb[(size_t)(cc - 0) * DM];
            const float s1 = SLb[(size_t)(cc - 1) * DM];
            const float s2 = SLb[(size_t)(cc - 2) * DM];
            const float s3 = SLb[(size_t)(cc - 3) * DM];
            const float q0 = p;
            const float q1 = q0 * lA[cc - 0];
            const float q2 = q1 * lA[cc - 1];
            const float q3 = q2 * lA[cc - 2];
            S = fmaf(s0, q0, S); Z = fmaf(lZ[cc - 0], q0, Z);
            S = fmaf(s1, q1, S); Z = fmaf(lZ[cc - 1], q1, Z);
            S = fmaf(s2, q2, S); Z = fmaf(lZ[cc - 2], q2, Z);
            S = fmaf(s3, q3, S); Z = fmaf(lZ[cc - 3], q3, Z);
            p = q3 * lA[cc - 3];
            cc -= 4;
            if (__builtin_amdgcn_readfirstlane(__float_as_uint(p)) == 0u) break;
        }
        if (__builtin_amdgcn_readfirstlane(__float_as_uint(p)) != 0u) {
            for (; cc >= 0; --cc) {
                S = fmaf(SLb[(size_t)cc * DM], p, S);
                Z = fmaf(lZ[cc], p, Z);
                p *= lA[cc];
            }
        }
    }

    const float* xr = x + ((size_t)b * TT + t0) * DIN;
    float* op = out + ((size_t)b * TT + t0) * DM + m;
    for (int tg = 0; tg < TC; tg += 4) {   // rolled, same as k_local
        const float4* xt0 = reinterpret_cast<const float4*>(xr + (size_t)(tg + 0) * DIN);
        const float4* xt1 = reinterpret_cast<const float4*>(xr + (size_t)(tg + 1) * DIN);
        const float4* xt2 = reinterpret_cast<const float4*>(xr + (size_t)(tg + 2) * DIN);
        const float4* xt3 = reinterpret_cast<const float4*>(xr + (size_t)(tg + 3) * DIN);
        float a0 = bm, a1 = bm, a2 = bm, a3 = bm;
#pragma unroll
        for (int k = 0; k < DIN / 4; ++k) {
            const float4 w = wv[k];
            const float4 v0 = xt0[k], v1 = xt1[k], v2 = xt2[k], v3 = xt3[k];
            a0 = fmaf(v0.x, w.x, a0); a0 = fmaf(v0.y, w.y, a0);
            a0 = fmaf(v0.z, w.z, a0); a0 = fmaf(v0.w, w.w, a0);
            a1 = fmaf(v1.x, w.x, a1); a1 = fmaf(v1.y, w.y, a1);
            a1 = fmaf(v1.z, w.z, a1); a1 = fmaf(v1.w, w.w, a1);
            a2 = fmaf(v2.x, w.x, a2); a2 = fmaf(v2.y, w.y, a2);
            a2 = fmaf(v2.z, w.z, a2); a2 = fmaf(v2.w, w.w, a2);
            a3 = fmaf(v3.x, w.x, a3); a3 = fmaf(v3.y, w.y, a3);
            a3 = fmaf(v3.z, w.z, a3); a3 = fmaf(v3.w, w.w, a3);
        }
        const float h0 = a0 > 0.f ? a0 : expm1f(a0);
        const float h1 = a1 > 0.f ? a1 : expm1f(a1);
        const float h2 = a2 > 0.f ? a2 : expm1f(a2);
        const float h3 = a3 > 0.f ? a3 : expm1f(a3);
        float d;
        d = as[tg + 0]; S = fmaf(d, S, h0); Z = fmaf(d, Z, 1.f);
        op[(size_t)(tg + 0) * DM] = S * __builtin_amdgcn_rcpf(Z);
        d = as[tg + 1]; S = fmaf(d, S, h1); Z = fmaf(d, Z, 1.f);
        op[(size_t)(tg + 1) * DM] = S * __builtin_amdgcn_rcpf(Z);
        d = as[tg + 2]; S = fmaf(d, S, h2); Z = fmaf(d, Z, 1.f);
        op[(size_t)(tg + 2) * DM] = S * __builtin_amdgcn_rcpf(Z);
        d = as[tg + 3]; S = fmaf(d, S, h3); Z = fmaf(d, Z, 1.f);
        op[(size_t)(tg + 3) * DM] = S * __builtin_amdgcn_rcpf(Z);
    }
}

extern "C" void kernel_launch(void* const* d_in, const int* in_sizes, int n_in,
                              void* d_out, int out_size, void* d_ws, size_t ws_size,
                              hipStream_t stream) {
    const float* x    = (const float*)d_in[0];  // [B,T,64]
    const float* tau  = (const float*)d_in[1];  // [B,T]
    const float* W    = (const float*)d_in[2];  // [256,64]
    const float* bias = (const float*)d_in[3];  // [256]
    const float* lamb = (const float*)d_in[4];  // [1]
    // beta (d_in[5]) cancels in softmax — unused.
    float* out = (float*)d_out;                 // [B,T,256] fp32

    float* ws = (float*)d_ws;
    float* SL = ws;                         // BB*NC*DM = 262,144 floats (1 MB)
    float* ZL = SL + (size_t)BB * NC * DM;  // BB*NC = 1024
    float* AK = ZL + BB * NC;               // BB*NC = 1024

    k_local<<<BB * NC, DM, 0, stream>>>(x, tau, W, bias, lamb, SL, ZL, AK);
    k_final<<<BB * NC, DM, 0, stream>>>(x, tau, W, bias, lamb, SL, ZL, AK, out);
}